// Round 4
// baseline (118.013 us; speedup 1.0000x reference)
//
#include <hip/hip_runtime.h>

#define B_DIM 8192
#define C_DIM 10000
#define C4    2500      // C_DIM / 4 (float4 groups)
#define NT    10        // column tiles of 256 float4 = 1024 columns
#define TILE4 256
#define NCHUNK 64       // row chunks
#define ROWCHUNK (B_DIM / NCHUNK)   // 128
#define NCH2  16        // second-level column-reduce partials

typedef float v4f __attribute__((ext_vector_type(4)));

// Fused main pass. Grid (NT, NCHUNK), block 256 (4 waves).
__global__ __launch_bounds__(256) void fused_main(
    const v4f* __restrict__ x4, const v4f* __restrict__ dm4,
    const int* __restrict__ target,
    v4f* __restrict__ colExpPart, v4f* __restrict__ colDPart,
    float* __restrict__ rowPartExp, float* __restrict__ rowPartDx,
    float* __restrict__ xt) {
    const int tile  = blockIdx.x;
    const int chunk = blockIdx.y;
    const int tid   = threadIdx.x;
    const int lane  = tid & 63;
    const int wave  = tid >> 6;
    const int base4 = tile * TILE4;
    const int row0  = chunk * ROWCHUNK;

    __shared__ int s_t[ROWCHUNK];
    __shared__ v4f sE[TILE4];
    __shared__ v4f sD[TILE4];

    for (int r = tid; r < ROWCHUNK; r += 256) s_t[r] = target[row0 + r];
    __syncthreads();

    int  col4[4];
    bool valid[4];
    v4f accE[4], accD[4];
#pragma unroll
    for (int it = 0; it < 4; ++it) {
        col4[it]  = base4 + it * 64 + lane;
        valid[it] = col4[it] < C4;
        accE[it] = (v4f){0.f, 0.f, 0.f, 0.f};
        accD[it] = (v4f){0.f, 0.f, 0.f, 0.f};
    }

    for (int r = wave; r < ROWCHUNK; r += 4) {
        const int row = row0 + r;
        const int t   = s_t[r];
        const v4f* xrow = x4 + (size_t)row * C4;
        const v4f* drow = dm4 + (size_t)t * C4;
        const int tq = t >> 2, tl = t & 3;
        float rowE = 0.f, rowDx = 0.f;
#pragma unroll
        for (int it = 0; it < 4; ++it) {
            if (!valid[it]) continue;
            // x is streamed exactly once: non-temporal (evict-first) so the
            // L2/L3 stay reserved for reused D rows.
            v4f xv = __builtin_nontemporal_load(&xrow[col4[it]]);
            v4f dv = drow[col4[it]];   // cached: D rows repeat across batch
            float ex = __expf(xv.x), ey = __expf(xv.y),
                  ez = __expf(xv.z), ew = __expf(xv.w);
            accE[it].x += ex; accE[it].y += ey; accE[it].z += ez; accE[it].w += ew;
            rowE += (ex + ey) + (ez + ew);
            accD[it].x += dv.x; accD[it].y += dv.y;
            accD[it].z += dv.z; accD[it].w += dv.w;
            rowDx += dv.x * xv.x + dv.y * xv.y + dv.z * xv.z + dv.w * xv.w;
            if (col4[it] == tq) {
                float v = (tl == 0) ? xv.x : (tl == 1) ? xv.y
                        : (tl == 2) ? xv.z : xv.w;
                xt[row] = v;
            }
        }
#pragma unroll
        for (int off = 32; off > 0; off >>= 1) {
            rowE  += __shfl_down(rowE, off, 64);
            rowDx += __shfl_down(rowDx, off, 64);
        }
        if (lane == 0) {
            rowPartExp[(size_t)tile * B_DIM + row] = rowE;
            rowPartDx [(size_t)tile * B_DIM + row] = rowDx;
        }
    }

    // Combine column partials across the 4 waves via LDS (deterministic).
    if (wave == 0) {
#pragma unroll
        for (int it = 0; it < 4; ++it) {
            sE[it * 64 + lane] = accE[it];
            sD[it * 64 + lane] = accD[it];
        }
    }
    __syncthreads();
    for (int w = 1; w < 4; ++w) {
        if (wave == w) {
#pragma unroll
            for (int it = 0; it < 4; ++it) {
                sE[it * 64 + lane] += accE[it];
                sD[it * 64 + lane] += accD[it];
            }
        }
        __syncthreads();
    }
    const int colg = base4 + tid;
    if (colg < C4) {
        colExpPart[(size_t)chunk * C4 + colg] = sE[tid];
        colDPart [(size_t)chunk * C4 + colg] = sD[tid];
    }
}

// Stage-A column reduce: NCHUNK -> NCH2 partials. Grid (10, NCH2), block 256.
__global__ __launch_bounds__(256) void col_reduceA(
    const v4f* __restrict__ colExpPart, const v4f* __restrict__ colDPart,
    v4f* __restrict__ colExp2, v4f* __restrict__ colD2) {
    const int col4 = blockIdx.x * 256 + threadIdx.x;
    const int part = blockIdx.y;
    if (col4 >= C4) return;
    const int per = NCHUNK / NCH2;           // 4
    const int c0  = part * per;
    v4f se = {0.f, 0.f, 0.f, 0.f};
    v4f sd = {0.f, 0.f, 0.f, 0.f};
    for (int c = c0; c < c0 + per; ++c) {
        se += __builtin_nontemporal_load(&colExpPart[(size_t)c * C4 + col4]);
        sd += __builtin_nontemporal_load(&colDPart [(size_t)c * C4 + col4]);
    }
    colExp2[(size_t)part * C4 + col4] = se;
    colD2 [(size_t)part * C4 + col4] = sd;
}

// Merged finalize. Grid 72 blocks x 256.
//  blocks 0..39 : column side. Each covers 64 col4 (4 threads per col4):
//                 sum NCH2 partials, colLSE=log(sum), t2 += S_j*colLSE_j.
//                 partials[b] = block t2 (double).
//  blocks 40..71: row side. i = (b-40)*256+tid: ce_i = log(sumExp_i)-xt_i.
//                 partials[40+s] = sum ce, partials[72+s] = sum dx.
__global__ __launch_bounds__(256) void fin_kernel(
    const v4f* __restrict__ colExp2, const v4f* __restrict__ colD2,
    const float* __restrict__ rowPartExp, const float* __restrict__ rowPartDx,
    const float* __restrict__ xt, double* __restrict__ partials) {
    const int b   = blockIdx.x;
    const int tid = threadIdx.x;
    __shared__ double sred[256];
    double mine = 0.0, mine2 = 0.0;

    if (b < 40) {
        const int col4 = b * 64 + (tid >> 2);
        const int sub  = tid & 3;
        v4f se = {0.f, 0.f, 0.f, 0.f};
        v4f sd = {0.f, 0.f, 0.f, 0.f};
        if (col4 < C4) {
            for (int c = sub; c < NCH2; c += 4) {
                se += colExp2[(size_t)c * C4 + col4];
                sd += colD2 [(size_t)c * C4 + col4];
            }
        }
        __shared__ v4f lE[256], lD[256];
        lE[tid] = se; lD[tid] = sd;
        __syncthreads();
        if (sub == 0 && col4 < C4) {
            v4f e = lE[tid] + lE[tid + 1] + lE[tid + 2] + lE[tid + 3];
            v4f d = lD[tid] + lD[tid + 1] + lD[tid + 2] + lD[tid + 3];
            mine = (double)d.x * (double)__logf(e.x)
                 + (double)d.y * (double)__logf(e.y)
                 + (double)d.z * (double)__logf(e.z)
                 + (double)d.w * (double)__logf(e.w);
        }
        sred[tid] = mine;
        __syncthreads();
        for (int s = 128; s > 0; s >>= 1) {
            if (tid < s) sred[tid] += sred[tid + s];
            __syncthreads();
        }
        if (tid == 0) partials[b] = sred[0];
    } else {
        const int s = b - 40;
        const int i = s * 256 + tid;          // < 8192 exactly
        float re = 0.f, rdx = 0.f;
#pragma unroll
        for (int t = 0; t < NT; ++t) {
            re  += rowPartExp[(size_t)t * B_DIM + i];
            rdx += rowPartDx [(size_t)t * B_DIM + i];
        }
        mine  = (double)(__logf(re) - xt[i]);
        mine2 = (double)rdx;
        __shared__ double sred2[256];
        sred[tid] = mine; sred2[tid] = mine2;
        __syncthreads();
        for (int st = 128; st > 0; st >>= 1) {
            if (tid < st) { sred[tid] += sred[tid + st]; sred2[tid] += sred2[tid + st]; }
            __syncthreads();
        }
        if (tid == 0) { partials[40 + s] = sred[0]; partials[72 + s] = sred2[0]; }
    }
}

__global__ void out_kernel(const double* __restrict__ partials,
                           float* __restrict__ out) {
    if (threadIdx.x == 0) {
        double t2 = 0.0, ce = 0.0, dx = 0.0;
        for (int b = 0; b < 40; ++b) t2 += partials[b];
        for (int b = 0; b < 32; ++b) ce += partials[40 + b];
        for (int b = 0; b < 32; ++b) dx += partials[72 + b];
        double ce_mean = ce / (double)B_DIM;
        double reg = -0.5 * (dx - t2) / ((double)C_DIM * (double)B_DIM);
        out[0] = (float)(ce_mean + reg);
    }
}

extern "C" void kernel_launch(void* const* d_in, const int* in_sizes, int n_in,
                              void* d_out, int out_size, void* d_ws, size_t ws_size,
                              hipStream_t stream) {
    const v4f* x4  = (const v4f*)d_in[0];
    const v4f* dm4 = (const v4f*)d_in[1];
    const int* target = (const int*)d_in[2];
    float* out = (float*)d_out;

    char* p = (char*)d_ws;
    auto alloc = [&](size_t bytes) {
        void* r = (void*)p;
        p += (bytes + 15) & ~(size_t)15;
        return r;
    };
    v4f*    colExpPart = (v4f*)alloc((size_t)NCHUNK * C4 * 16);
    v4f*    colDPart   = (v4f*)alloc((size_t)NCHUNK * C4 * 16);
    v4f*    colExp2    = (v4f*)alloc((size_t)NCH2 * C4 * 16);
    v4f*    colD2      = (v4f*)alloc((size_t)NCH2 * C4 * 16);
    float*  rowPartExp = (float*)alloc((size_t)NT * B_DIM * 4);
    float*  rowPartDx  = (float*)alloc((size_t)NT * B_DIM * 4);
    float*  xt         = (float*)alloc((size_t)B_DIM * 4);
    double* partials   = (double*)alloc(104 * 8);

    fused_main<<<dim3(NT, NCHUNK), 256, 0, stream>>>(
        x4, dm4, target, colExpPart, colDPart, rowPartExp, rowPartDx, xt);
    col_reduceA<<<dim3(10, NCH2), 256, 0, stream>>>(
        colExpPart, colDPart, colExp2, colD2);
    fin_kernel<<<72, 256, 0, stream>>>(
        colExp2, colD2, rowPartExp, rowPartDx, xt, partials);
    out_kernel<<<1, 64, 0, stream>>>(partials, out);
}

// Round 5
// 111.687 us; speedup vs baseline: 1.0566x; 1.0566x over previous
//
#include <hip/hip_runtime.h>

#define B_DIM 8192
#define C_DIM 10000
#define C4    2500      // C_DIM / 4 (float4 groups)
#define NT    10        // column tiles of 256 float4 = 1024 columns
#define TILE4 256
#define NCHUNK 128      // row chunks -> grid 10x128 = 1280 blocks = 5/CU exact
#define ROWCHUNK (B_DIM / NCHUNK)   // 64
#define NCH2  16        // second-level column-reduce partials (per = 8)

typedef float v4f __attribute__((ext_vector_type(4)));

// Fused main pass. Grid (NT, NCHUNK), block 256 (4 waves).
__global__ __launch_bounds__(256) void fused_main(
    const v4f* __restrict__ x4, const v4f* __restrict__ dm4,
    const int* __restrict__ target,
    v4f* __restrict__ colExpPart, v4f* __restrict__ colDPart,
    float* __restrict__ rowPartExp, float* __restrict__ rowPartDx,
    float* __restrict__ xt) {
    const int tile  = blockIdx.x;
    const int chunk = blockIdx.y;
    const int tid   = threadIdx.x;
    const int lane  = tid & 63;
    const int wave  = tid >> 6;
    const int base4 = tile * TILE4;
    const int row0  = chunk * ROWCHUNK;

    __shared__ int s_t[ROWCHUNK];
    __shared__ v4f sE[TILE4];
    __shared__ v4f sD[TILE4];

    for (int r = tid; r < ROWCHUNK; r += 256) s_t[r] = target[row0 + r];
    __syncthreads();

    int  col4[4];
    bool valid[4];
    v4f accE[4], accD[4];
#pragma unroll
    for (int it = 0; it < 4; ++it) {
        col4[it]  = base4 + it * 64 + lane;
        valid[it] = col4[it] < C4;
        accE[it] = (v4f){0.f, 0.f, 0.f, 0.f};
        accD[it] = (v4f){0.f, 0.f, 0.f, 0.f};
    }

    for (int r = wave; r < ROWCHUNK; r += 4) {
        const int row = row0 + r;
        const int t   = s_t[r];
        const v4f* xrow = x4 + (size_t)row * C4;
        const v4f* drow = dm4 + (size_t)t * C4;
        const int tq = t >> 2, tl = t & 3;
        float rowE = 0.f, rowDx = 0.f;
#pragma unroll
        for (int it = 0; it < 4; ++it) {
            if (!valid[it]) continue;
            // x is streamed exactly once: non-temporal (evict-first) so the
            // L2/L3 stay reserved for reused D rows.
            v4f xv = __builtin_nontemporal_load(&xrow[col4[it]]);
            v4f dv = drow[col4[it]];   // cached: D rows repeat across batch
            float ex = __expf(xv.x), ey = __expf(xv.y),
                  ez = __expf(xv.z), ew = __expf(xv.w);
            accE[it].x += ex; accE[it].y += ey; accE[it].z += ez; accE[it].w += ew;
            rowE += (ex + ey) + (ez + ew);
            accD[it].x += dv.x; accD[it].y += dv.y;
            accD[it].z += dv.z; accD[it].w += dv.w;
            rowDx += dv.x * xv.x + dv.y * xv.y + dv.z * xv.z + dv.w * xv.w;
            if (col4[it] == tq) {
                float v = (tl == 0) ? xv.x : (tl == 1) ? xv.y
                        : (tl == 2) ? xv.z : xv.w;
                xt[row] = v;
            }
        }
#pragma unroll
        for (int off = 32; off > 0; off >>= 1) {
            rowE  += __shfl_down(rowE, off, 64);
            rowDx += __shfl_down(rowDx, off, 64);
        }
        if (lane == 0) {
            rowPartExp[(size_t)tile * B_DIM + row] = rowE;
            rowPartDx [(size_t)tile * B_DIM + row] = rowDx;
        }
    }

    // Combine column partials across the 4 waves via LDS (deterministic).
    if (wave == 0) {
#pragma unroll
        for (int it = 0; it < 4; ++it) {
            sE[it * 64 + lane] = accE[it];
            sD[it * 64 + lane] = accD[it];
        }
    }
    __syncthreads();
    for (int w = 1; w < 4; ++w) {
        if (wave == w) {
#pragma unroll
            for (int it = 0; it < 4; ++it) {
                sE[it * 64 + lane] += accE[it];
                sD[it * 64 + lane] += accD[it];
            }
        }
        __syncthreads();
    }
    const int colg = base4 + tid;
    if (colg < C4) {
        colExpPart[(size_t)chunk * C4 + colg] = sE[tid];
        colDPart [(size_t)chunk * C4 + colg] = sD[tid];
    }
}

// Stage-A column reduce: NCHUNK -> NCH2 partials. Grid (10, NCH2), block 256.
__global__ __launch_bounds__(256) void col_reduceA(
    const v4f* __restrict__ colExpPart, const v4f* __restrict__ colDPart,
    v4f* __restrict__ colExp2, v4f* __restrict__ colD2) {
    const int col4 = blockIdx.x * 256 + threadIdx.x;
    const int part = blockIdx.y;
    if (col4 >= C4) return;
    const int per = NCHUNK / NCH2;           // 8
    const int c0  = part * per;
    v4f se = {0.f, 0.f, 0.f, 0.f};
    v4f sd = {0.f, 0.f, 0.f, 0.f};
    for (int c = c0; c < c0 + per; ++c) {
        se += __builtin_nontemporal_load(&colExpPart[(size_t)c * C4 + col4]);
        sd += __builtin_nontemporal_load(&colDPart [(size_t)c * C4 + col4]);
    }
    colExp2[(size_t)part * C4 + col4] = se;
    colD2 [(size_t)part * C4 + col4] = sd;
}

// Merged finalize. Grid 72 blocks x 256.
//  blocks 0..39 : column side (64 col4 each, 4 threads per col4).
//  blocks 40..71: row side (256 rows each).
__global__ __launch_bounds__(256) void fin_kernel(
    const v4f* __restrict__ colExp2, const v4f* __restrict__ colD2,
    const float* __restrict__ rowPartExp, const float* __restrict__ rowPartDx,
    const float* __restrict__ xt, double* __restrict__ partials) {
    const int b   = blockIdx.x;
    const int tid = threadIdx.x;
    __shared__ double sred[256];
    double mine = 0.0, mine2 = 0.0;

    if (b < 40) {
        const int col4 = b * 64 + (tid >> 2);
        const int sub  = tid & 3;
        v4f se = {0.f, 0.f, 0.f, 0.f};
        v4f sd = {0.f, 0.f, 0.f, 0.f};
        if (col4 < C4) {
            for (int c = sub; c < NCH2; c += 4) {
                se += colExp2[(size_t)c * C4 + col4];
                sd += colD2 [(size_t)c * C4 + col4];
            }
        }
        __shared__ v4f lE[256], lD[256];
        lE[tid] = se; lD[tid] = sd;
        __syncthreads();
        if (sub == 0 && col4 < C4) {
            v4f e = lE[tid] + lE[tid + 1] + lE[tid + 2] + lE[tid + 3];
            v4f d = lD[tid] + lD[tid + 1] + lD[tid + 2] + lD[tid + 3];
            mine = (double)d.x * (double)__logf(e.x)
                 + (double)d.y * (double)__logf(e.y)
                 + (double)d.z * (double)__logf(e.z)
                 + (double)d.w * (double)__logf(e.w);
        }
        sred[tid] = mine;
        __syncthreads();
        for (int s = 128; s > 0; s >>= 1) {
            if (tid < s) sred[tid] += sred[tid + s];
            __syncthreads();
        }
        if (tid == 0) partials[b] = sred[0];
    } else {
        const int s = b - 40;
        const int i = s * 256 + tid;          // < 8192 exactly
        float re = 0.f, rdx = 0.f;
#pragma unroll
        for (int t = 0; t < NT; ++t) {
            re  += rowPartExp[(size_t)t * B_DIM + i];
            rdx += rowPartDx [(size_t)t * B_DIM + i];
        }
        mine  = (double)(__logf(re) - xt[i]);
        mine2 = (double)rdx;
        __shared__ double sred2[256];
        sred[tid] = mine; sred2[tid] = mine2;
        __syncthreads();
        for (int st = 128; st > 0; st >>= 1) {
            if (tid < st) { sred[tid] += sred[tid + st]; sred2[tid] += sred2[tid + st]; }
            __syncthreads();
        }
        if (tid == 0) { partials[40 + s] = sred[0]; partials[72 + s] = sred2[0]; }
    }
}

__global__ void out_kernel(const double* __restrict__ partials,
                           float* __restrict__ out) {
    if (threadIdx.x == 0) {
        double t2 = 0.0, ce = 0.0, dx = 0.0;
        for (int b = 0; b < 40; ++b) t2 += partials[b];
        for (int b = 0; b < 32; ++b) ce += partials[40 + b];
        for (int b = 0; b < 32; ++b) dx += partials[72 + b];
        double ce_mean = ce / (double)B_DIM;
        double reg = -0.5 * (dx - t2) / ((double)C_DIM * (double)B_DIM);
        out[0] = (float)(ce_mean + reg);
    }
}

extern "C" void kernel_launch(void* const* d_in, const int* in_sizes, int n_in,
                              void* d_out, int out_size, void* d_ws, size_t ws_size,
                              hipStream_t stream) {
    const v4f* x4  = (const v4f*)d_in[0];
    const v4f* dm4 = (const v4f*)d_in[1];
    const int* target = (const int*)d_in[2];
    float* out = (float*)d_out;

    char* p = (char*)d_ws;
    auto alloc = [&](size_t bytes) {
        void* r = (void*)p;
        p += (bytes + 15) & ~(size_t)15;
        return r;
    };
    v4f*    colExpPart = (v4f*)alloc((size_t)NCHUNK * C4 * 16);
    v4f*    colDPart   = (v4f*)alloc((size_t)NCHUNK * C4 * 16);
    v4f*    colExp2    = (v4f*)alloc((size_t)NCH2 * C4 * 16);
    v4f*    colD2      = (v4f*)alloc((size_t)NCH2 * C4 * 16);
    float*  rowPartExp = (float*)alloc((size_t)NT * B_DIM * 4);
    float*  rowPartDx  = (float*)alloc((size_t)NT * B_DIM * 4);
    float*  xt         = (float*)alloc((size_t)B_DIM * 4);
    double* partials   = (double*)alloc(104 * 8);

    fused_main<<<dim3(NT, NCHUNK), 256, 0, stream>>>(
        x4, dm4, target, colExpPart, colDPart, rowPartExp, rowPartDx, xt);
    col_reduceA<<<dim3(10, NCH2), 256, 0, stream>>>(
        colExpPart, colDPart, colExp2, colD2);
    fin_kernel<<<72, 256, 0, stream>>>(
        colExp2, colD2, rowPartExp, rowPartDx, xt, partials);
    out_kernel<<<1, 64, 0, stream>>>(partials, out);
}

// Round 6
// 110.366 us; speedup vs baseline: 1.0693x; 1.0120x over previous
//
#include <hip/hip_runtime.h>

#define B_DIM 8192
#define C_DIM 10000
#define C4    2500      // C_DIM / 4 (float4 groups)
#define NT    10        // column tiles of 256 float4 = 1024 columns
#define TILE4 256
#define NCHUNK 128      // row chunks -> grid 10x128 = 1280 blocks = 5/CU exact
#define ROWCHUNK (B_DIM / NCHUNK)   // 64
#define NCB   157       // column blocks in fin2 (ceil(2500/16))

typedef float v4f __attribute__((ext_vector_type(4)));

// Fused main pass. Grid (NT, NCHUNK), block 256 (4 waves). UNCHANGED from r5.
__global__ __launch_bounds__(256) void fused_main(
    const v4f* __restrict__ x4, const v4f* __restrict__ dm4,
    const int* __restrict__ target,
    v4f* __restrict__ colExpPart, v4f* __restrict__ colDPart,
    float* __restrict__ rowPartExp, float* __restrict__ rowPartDx,
    float* __restrict__ xt) {
    const int tile  = blockIdx.x;
    const int chunk = blockIdx.y;
    const int tid   = threadIdx.x;
    const int lane  = tid & 63;
    const int wave  = tid >> 6;
    const int base4 = tile * TILE4;
    const int row0  = chunk * ROWCHUNK;

    __shared__ int s_t[ROWCHUNK];
    __shared__ v4f sE[TILE4];
    __shared__ v4f sD[TILE4];

    for (int r = tid; r < ROWCHUNK; r += 256) s_t[r] = target[row0 + r];
    __syncthreads();

    int  col4[4];
    bool valid[4];
    v4f accE[4], accD[4];
#pragma unroll
    for (int it = 0; it < 4; ++it) {
        col4[it]  = base4 + it * 64 + lane;
        valid[it] = col4[it] < C4;
        accE[it] = (v4f){0.f, 0.f, 0.f, 0.f};
        accD[it] = (v4f){0.f, 0.f, 0.f, 0.f};
    }

    for (int r = wave; r < ROWCHUNK; r += 4) {
        const int row = row0 + r;
        const int t   = s_t[r];
        const v4f* xrow = x4 + (size_t)row * C4;
        const v4f* drow = dm4 + (size_t)t * C4;
        const int tq = t >> 2, tl = t & 3;
        float rowE = 0.f, rowDx = 0.f;
#pragma unroll
        for (int it = 0; it < 4; ++it) {
            if (!valid[it]) continue;
            // x is streamed exactly once: non-temporal (evict-first) so the
            // L2/L3 stay reserved for reused D rows.
            v4f xv = __builtin_nontemporal_load(&xrow[col4[it]]);
            v4f dv = drow[col4[it]];   // cached: D rows repeat across batch
            float ex = __expf(xv.x), ey = __expf(xv.y),
                  ez = __expf(xv.z), ew = __expf(xv.w);
            accE[it].x += ex; accE[it].y += ey; accE[it].z += ez; accE[it].w += ew;
            rowE += (ex + ey) + (ez + ew);
            accD[it].x += dv.x; accD[it].y += dv.y;
            accD[it].z += dv.z; accD[it].w += dv.w;
            rowDx += dv.x * xv.x + dv.y * xv.y + dv.z * xv.z + dv.w * xv.w;
            if (col4[it] == tq) {
                float v = (tl == 0) ? xv.x : (tl == 1) ? xv.y
                        : (tl == 2) ? xv.z : xv.w;
                xt[row] = v;
            }
        }
#pragma unroll
        for (int off = 32; off > 0; off >>= 1) {
            rowE  += __shfl_down(rowE, off, 64);
            rowDx += __shfl_down(rowDx, off, 64);
        }
        if (lane == 0) {
            rowPartExp[(size_t)tile * B_DIM + row] = rowE;
            rowPartDx [(size_t)tile * B_DIM + row] = rowDx;
        }
    }

    // Combine column partials across the 4 waves via LDS (deterministic).
    if (wave == 0) {
#pragma unroll
        for (int it = 0; it < 4; ++it) {
            sE[it * 64 + lane] = accE[it];
            sD[it * 64 + lane] = accD[it];
        }
    }
    __syncthreads();
    for (int w = 1; w < 4; ++w) {
        if (wave == w) {
#pragma unroll
            for (int it = 0; it < 4; ++it) {
                sE[it * 64 + lane] += accE[it];
                sD[it * 64 + lane] += accD[it];
            }
        }
        __syncthreads();
    }
    const int colg = base4 + tid;
    if (colg < C4) {
        colExpPart[(size_t)chunk * C4 + colg] = sE[tid];
        colDPart [(size_t)chunk * C4 + colg] = sD[tid];
    }
}

// Single merged finalize. Grid NCB+32 = 189 blocks x 256.
//  blocks 0..NCB-1 : column side. Block b covers 16 col4 (64 columns).
//    Thread layout (cl = tid&15 -> col4, q = tid>>4 -> chunk lane): each
//    (cl,q) sums chunks q, q+16, ..., q+112 of colExpPart/colDPart, then an
//    LDS tree over q yields full column sums; 16 threads (q==0) compute
//    colLSE = log(sumExp) and t2 += S_j * colLSE_j; block-reduce -> partials[b].
//  blocks NCB..NCB+31 : row side. i = (b-NCB)*256+tid:
//    ce_i = log(sumExp_i) - xt_i; dx_i. -> partials[NCB+s], partials[NCB+32+s].
__global__ __launch_bounds__(256) void fin2_kernel(
    const v4f* __restrict__ colExpPart, const v4f* __restrict__ colDPart,
    const float* __restrict__ rowPartExp, const float* __restrict__ rowPartDx,
    const float* __restrict__ xt, double* __restrict__ partials) {
    const int b   = blockIdx.x;
    const int tid = threadIdx.x;
    __shared__ double sred[256];

    if (b < NCB) {
        const int cl   = tid & 15;
        const int q    = tid >> 4;           // 0..15
        const int col4 = b * 16 + cl;
        v4f se = {0.f, 0.f, 0.f, 0.f};
        v4f sd = {0.f, 0.f, 0.f, 0.f};
        if (col4 < C4) {
            for (int c = q; c < NCHUNK; c += 16) {
                se += __builtin_nontemporal_load(&colExpPart[(size_t)c * C4 + col4]);
                sd += __builtin_nontemporal_load(&colDPart [(size_t)c * C4 + col4]);
            }
        }
        __shared__ v4f lE[256], lD[256];
        lE[tid] = se; lD[tid] = sd;
        __syncthreads();
        for (int s = 8; s > 0; s >>= 1) {     // tree over q
            if (q < s) { lE[tid] += lE[tid + s * 16]; lD[tid] += lD[tid + s * 16]; }
            __syncthreads();
        }
        double mine = 0.0;
        if (q == 0 && col4 < C4) {
            v4f e = lE[tid];
            v4f d = lD[tid];
            mine = (double)d.x * (double)__logf(e.x)
                 + (double)d.y * (double)__logf(e.y)
                 + (double)d.z * (double)__logf(e.z)
                 + (double)d.w * (double)__logf(e.w);
        }
        sred[tid] = mine;
        __syncthreads();
        for (int s = 128; s > 0; s >>= 1) {
            if (tid < s) sred[tid] += sred[tid + s];
            __syncthreads();
        }
        if (tid == 0) partials[b] = sred[0];
    } else {
        const int s = b - NCB;
        const int i = s * 256 + tid;          // < 8192 exactly
        float re = 0.f, rdx = 0.f;
#pragma unroll
        for (int t = 0; t < NT; ++t) {
            re  += rowPartExp[(size_t)t * B_DIM + i];
            rdx += rowPartDx [(size_t)t * B_DIM + i];
        }
        double mine  = (double)(__logf(re) - xt[i]);
        double mine2 = (double)rdx;
        __shared__ double sred2[256];
        sred[tid] = mine; sred2[tid] = mine2;
        __syncthreads();
        for (int st = 128; st > 0; st >>= 1) {
            if (tid < st) { sred[tid] += sred[tid + st]; sred2[tid] += sred2[tid + st]; }
            __syncthreads();
        }
        if (tid == 0) { partials[NCB + s] = sred[0]; partials[NCB + 32 + s] = sred2[0]; }
    }
}

// Final combine: one 64-thread wave, shuffle-reduce in double.
__global__ void out_kernel(const double* __restrict__ partials,
                           float* __restrict__ out) {
    const int tid = threadIdx.x;   // 64 threads = 1 wave
    double t2 = 0.0, ce = 0.0, dx = 0.0;
    for (int i = tid; i < NCB; i += 64) t2 += partials[i];
    if (tid < 32) {
        ce = partials[NCB + tid];
        dx = partials[NCB + 32 + tid];
    }
#pragma unroll
    for (int off = 32; off > 0; off >>= 1) {
        t2 += __shfl_down(t2, off, 64);
        ce += __shfl_down(ce, off, 64);
        dx += __shfl_down(dx, off, 64);
    }
    if (tid == 0) {
        double ce_mean = ce / (double)B_DIM;
        double reg = -0.5 * (dx - t2) / ((double)C_DIM * (double)B_DIM);
        out[0] = (float)(ce_mean + reg);
    }
}

extern "C" void kernel_launch(void* const* d_in, const int* in_sizes, int n_in,
                              void* d_out, int out_size, void* d_ws, size_t ws_size,
                              hipStream_t stream) {
    const v4f* x4  = (const v4f*)d_in[0];
    const v4f* dm4 = (const v4f*)d_in[1];
    const int* target = (const int*)d_in[2];
    float* out = (float*)d_out;

    char* p = (char*)d_ws;
    auto alloc = [&](size_t bytes) {
        void* r = (void*)p;
        p += (bytes + 15) & ~(size_t)15;
        return r;
    };
    v4f*    colExpPart = (v4f*)alloc((size_t)NCHUNK * C4 * 16);
    v4f*    colDPart   = (v4f*)alloc((size_t)NCHUNK * C4 * 16);
    float*  rowPartExp = (float*)alloc((size_t)NT * B_DIM * 4);
    float*  rowPartDx  = (float*)alloc((size_t)NT * B_DIM * 4);
    float*  xt         = (float*)alloc((size_t)B_DIM * 4);
    double* partials   = (double*)alloc((NCB + 64) * 8);

    fused_main<<<dim3(NT, NCHUNK), 256, 0, stream>>>(
        x4, dm4, target, colExpPart, colDPart, rowPartExp, rowPartDx, xt);
    fin2_kernel<<<NCB + 32, 256, 0, stream>>>(
        colExpPart, colDPart, rowPartExp, rowPartDx, xt, partials);
    out_kernel<<<1, 64, 0, stream>>>(partials, out);
}